// Round 5
// baseline (438.963 us; speedup 1.0000x reference)
//
#include <hip/hip_runtime.h>

// Spatial_15968688406784: masked 4x4 block-sum -> gate -> gated copy.
// N=64, C=64, H_IN=110, H_PAD=112, P=4.
//
// Round 5: round-3b structure (quarter-plane LDS staging, all-float4 NT
// global access) +
//  (a) skip mask pad-row loads for the last quarter (zero-fill LDS instead;
//      those rows only ever multiply x==0),
//  (b) writeback from REGISTERS: staging and writeback touch the same
//      i = tid + k*256 elements, so keep the staged f4s in xr_reg[] and
//      skip the post-barrier LDS re-read (removes lgkmcnt stalls in the
//      store path). LDS sx is kept only for the gate compute.
// History: R1 no-LDS 8B = 154us; R2 LDS 16B = 154us; R3b +NT = <124us
// (kernel fell out of rocprof top-5; harness 822MB fills at ~125us now rank
// above it). Wall was L3 write-allocation thrash, fixed by NT.

typedef float f4 __attribute__((ext_vector_type(4)));

#define HIN     110
#define HPAD    112
#define PLANE_X 12100           // 110*110
#define PLANE_M 12544           // 112*112
#define QROWS   28              // x rows per block (7 tile-rows)
#define QX      (QROWS*HIN)     // 3080
#define QX4     (QX/4)          // 770
#define QM      (QROWS*HPAD)    // 3136
#define QM4     (QM/4)          // 784
#define NTILES  196             // 7*28 pooled tiles per block

__global__ __launch_bounds__(256) void spatial_gate_kernel(
    const float* __restrict__ x,
    const float* __restrict__ mask,
    float* __restrict__ out)
{
    __shared__ __align__(16) float sx[QX];   // 12320 B
    __shared__ __align__(16) float sm[QM];   // 12544 B
    __shared__ float sg[NTILES];             //   784 B

    const int tid = threadIdx.x;
    const unsigned blk   = blockIdx.x;
    const unsigned plane = blk >> 2;
    const unsigned q     = blk & 3;
    const int r0    = (int)q * QROWS;                           // 0,28,56,84
    const int vrows = (r0 + QROWS <= HIN) ? QROWS : (HIN - r0); // 28,28,28,26
    const int nval  = vrows * HIN;                              // 3080 or 2860
    const int nval4 = nval >> 2;                                // 770 or 715
    const int mval4 = (vrows * HPAD) >> 2;                      // 784 or 728

    const f4* __restrict__ xg = (const f4*)(x    + (size_t)plane*PLANE_X + (size_t)r0*HIN);
    const f4* __restrict__ mg = (const f4*)(mask + (size_t)plane*PLANE_M + (size_t)r0*HPAD);
    f4*       __restrict__ og = (f4*)      (out  + (size_t)plane*PLANE_X + (size_t)r0*HIN);
    f4* sx4 = (f4*)sx;
    f4* sm4 = (f4*)sm;

    // ---- stage: contiguous NT float4 global->LDS, x copies kept in regs ----
    f4 xr_reg[4];
    {
        int k = 0;
        for (int i = tid; i < QX4; i += 256, ++k) {
            f4 v;
            if (i < nval4) v = __builtin_nontemporal_load(&xg[i]);
            else           v = (f4){0.f, 0.f, 0.f, 0.f};
            xr_reg[k] = v;
            sx4[i] = v;
        }
    }
    for (int i = tid; i < mval4; i += 256) sm4[i] = __builtin_nontemporal_load(&mg[i]);
    // mask pad rows (q==3 only): never loaded; zero them so 0*garbage can't NaN
    for (int i = mval4 + tid; i < QM4; i += 256) sm4[i] = (f4){0.f, 0.f, 0.f, 0.f};
    __syncthreads();

    // ---- gate compute: one thread per 4x4 tile ----
    if (tid < NTILES) {
        const int tr   = tid / 28;
        const int tc   = tid - tr * 28;
        const int col0 = tc * 4;
        float total = 0.f;
        #pragma unroll
        for (int r = 0; r < 4; ++r) {
            const int lr = tr * 4 + r;
            const float* xr = sx + lr * HIN;
            const float* mr = sm + lr * HPAD + col0;
            float p[4];
            #pragma unroll
            for (int j = 0; j < 4; ++j) {
                const int c  = col0 + j;
                const int cs = (c < HIN) ? c : 0;   // safe in-bounds index
                float xv = xr[cs];
                xv = (c < HIN) ? xv : 0.f;          // cols 110,111 are pad -> 0
                // explicit rounding: no FMA contraction, match numpy bitwise
                p[j] = __fmul_rn(xv, mr[j]);
            }
            // numpy order: cols sequential, then rows sequential
            const float rs = __fadd_rn(__fadd_rn(__fadd_rn(p[0], p[1]), p[2]), p[3]);
            total = __fadd_rn(total, rs);
        }
        sg[tid] = (total > 0.f) ? 1.f : 0.f;
    }
    __syncthreads();

    // ---- gated writeback from registers, NT float4 stores ----
    {
        int k = 0;
        for (int i4 = tid; i4 < nval4; i4 += 256, ++k) {
            const f4 v = xr_reg[k];
            const int i = i4 << 2;
            f4 o;
            #pragma unroll
            for (int j = 0; j < 4; ++j) {
                const int idx = i + j;
                const int row = idx / HIN;            // const divisor -> mulhi
                const int col = idx - row * HIN;
                o[j] = v[j] * sg[(row >> 2) * 28 + (col >> 2)];
            }
            __builtin_nontemporal_store(o, &og[i4]);
        }
    }
}

extern "C" void kernel_launch(void* const* d_in, const int* in_sizes, int n_in,
                              void* d_out, int out_size, void* d_ws, size_t ws_size,
                              hipStream_t stream) {
    const float* x    = (const float*)d_in[0];
    const float* mask = (const float*)d_in[1];
    // d_in[2] is p_size == 4, baked into the kernel constants.
    float* out = (float*)d_out;

    dim3 grid(4096u * 4u);   // one block per quarter-plane
    dim3 block(256);
    hipLaunchKernelGGL(spatial_gate_kernel, grid, block, 0, stream, x, mask, out);
}